// Round 7
// baseline (134.567 us; speedup 1.0000x reference)
//
#include <hip/hip_runtime.h>

// GridInterpolator: trilinear interpolation over 8 voxel grids.
// vox: [8, 96, 96, 96, 16] f32, gidx: [N,1] i32, pts: [N,3] f32 -> out: [N,16] f32
//
// Dense one-pass gather, 4 threads per feature-quad as in round 6, but each
// thread now handles TWO points (p and p+N/2): 16 independent dwordx4 corner
// gathers in flight per thread -> 2x memory-level parallelism per wave.
// Byte traffic unchanged; stores are two contiguous 1-KB wave segments.

#define GDIM  96
#define NFEAT 16

typedef float f32x4 __attribute__((ext_vector_type(4)));

__device__ __forceinline__ int clampi(int v, int lo, int hi) {
    return v < lo ? lo : (v > hi ? hi : v);
}

struct PtSetup {
    int   gbase;
    int   bx, by, bz;
    float fx, fy, fz;
    bool  inside;
};

__device__ __forceinline__ PtSetup setup_point(const int* __restrict__ gidx,
                                               const float* __restrict__ pts,
                                               int p) {
    PtSetup s;
    const float px = __builtin_nontemporal_load(&pts[p * 3 + 0]);
    const float py = __builtin_nontemporal_load(&pts[p * 3 + 1]);
    const float pz = __builtin_nontemporal_load(&pts[p * 3 + 2]);
    const int   gi = __builtin_nontemporal_load(&gidx[p]);

    const float ux = (px + 1.0f) * 0.5f;
    const float uy = (py + 1.0f) * 0.5f;
    const float uz = (pz + 1.0f) * 0.5f;
    s.inside = (ux >= 0.0f) & (ux <= 1.0f) &
               (uy >= 0.0f) & (uy <= 1.0f) &
               (uz >= 0.0f) & (uz <= 1.0f);

    const float sx = ux * (float)(GDIM - 1);
    const float sy = uy * (float)(GDIM - 1);
    const float sz = uz * (float)(GDIM - 1);
    s.bx = (int)sx; s.by = (int)sy; s.bz = (int)sz;
    s.fx = sx - (float)s.bx;
    s.fy = sy - (float)s.by;
    s.fz = sz - (float)s.bz;
    s.gbase = gi * (GDIM * GDIM * GDIM);
    return s;
}

__device__ __forceinline__ size_t corner_addr(const PtSetup& s, int k, int fq) {
    const int ox = k & 1, oy = (k >> 1) & 1, oz = (k >> 2) & 1;
    const int cx = clampi(s.bx + ox, 0, GDIM - 1);
    const int cy = clampi(s.by + oy, 0, GDIM - 1);
    const int cz = clampi(s.bz + oz, 0, GDIM - 1);
    const int cell = s.gbase + cx * (GDIM * GDIM) + cy * GDIM + cz;
    return (size_t)(cell << 2) + fq;
}

__device__ __forceinline__ float corner_w(const PtSetup& s, int k) {
    const int ox = k & 1, oy = (k >> 1) & 1, oz = (k >> 2) & 1;
    return (ox ? s.fx : 1.0f - s.fx) *
           (oy ? s.fy : 1.0f - s.fy) *
           (oz ? s.fz : 1.0f - s.fz);
}

__global__ __launch_bounds__(256) void grid_interp_2p(
    const f32x4* __restrict__ vox4,
    const int*   __restrict__ gidx,
    const float* __restrict__ pts,
    f32x4*       __restrict__ out4,
    int n_pts, int half)
{
    const int tid = blockIdx.x * blockDim.x + threadIdx.x;
    if (tid >= half * 4) return;

    const int p0 = tid >> 2;
    const int fq = tid & 3;
    const int p1 = p0 + half;
    const bool has1 = (p1 < n_pts);

    const PtSetup s0 = setup_point(gidx, pts, p0);
    const PtSetup s1 = setup_point(gidx, pts, has1 ? p1 : p0);

    float a0x = 0.f, a0y = 0.f, a0z = 0.f, a0w = 0.f;
    float a1x = 0.f, a1y = 0.f, a1z = 0.f, a1w = 0.f;
#pragma unroll
    for (int k = 0; k < 8; ++k) {
        const f32x4 v0 = vox4[corner_addr(s0, k, fq)];
        const f32x4 v1 = vox4[corner_addr(s1, k, fq)];
        const float w0 = corner_w(s0, k);
        const float w1 = corner_w(s1, k);
        a0x = fmaf(v0.x, w0, a0x);
        a0y = fmaf(v0.y, w0, a0y);
        a0z = fmaf(v0.z, w0, a0z);
        a0w = fmaf(v0.w, w0, a0w);
        a1x = fmaf(v1.x, w1, a1x);
        a1y = fmaf(v1.y, w1, a1y);
        a1z = fmaf(v1.z, w1, a1z);
        a1w = fmaf(v1.w, w1, a1w);
    }

    f32x4 r0;
    r0.x = s0.inside ? a0x : 0.f;
    r0.y = s0.inside ? a0y : 0.f;
    r0.z = s0.inside ? a0z : 0.f;
    r0.w = s0.inside ? a0w : 0.f;
    __builtin_nontemporal_store(r0, &out4[tid]);

    if (has1) {
        f32x4 r1;
        r1.x = s1.inside ? a1x : 0.f;
        r1.y = s1.inside ? a1y : 0.f;
        r1.z = s1.inside ? a1z : 0.f;
        r1.w = s1.inside ? a1w : 0.f;
        __builtin_nontemporal_store(r1, &out4[(size_t)p1 * 4 + fq]);
    }
}

extern "C" void kernel_launch(void* const* d_in, const int* in_sizes, int n_in,
                              void* d_out, int out_size, void* d_ws, size_t ws_size,
                              hipStream_t stream) {
    const f32x4* vox4 = (const f32x4*)d_in[0];
    const int*   gidx = (const int*)  d_in[1];
    const float* pts  = (const float*)d_in[2];
    f32x4*       out4 = (f32x4*)d_out;

    const int n_pts = in_sizes[1];        // N
    const int half  = (n_pts + 1) >> 1;
    const int n_thr = half * 4;

    const int threads = 256;
    const int blocks  = (n_thr + threads - 1) / threads;  // 8192 at N=1M

    grid_interp_2p<<<blocks, threads, 0, stream>>>(vox4, gidx, pts, out4, n_pts, half);
}

// Round 8
// 133.334 us; speedup vs baseline: 1.0092x; 1.0092x over previous
//
#include <hip/hip_runtime.h>

// GridInterpolator: trilinear interpolation over 8 voxel grids.
// vox: [8, 96, 96, 96, 16] f32, gidx: [N,1] i32, pts: [N,3] f32 -> out: [N,16] f32
//
// Dense one-pass gather. 4 threads per point (one per feature-quad); each
// thread issues 8 float4 (dwordx4) corner loads. The 4 lanes of a point
// together read each corner's full 64-B cell -> one coalesced segment.
// out/pts/gidx are single-use streams: nontemporal so L2/L3 stay dedicated
// to the 432-MiB voxel table.
//
// Regime (measured R1-R7): random-gather DRAM efficiency bound at ~4-4.6 TB/s
// effective. MLP x2 flat (R7); vmem-instruction x4 reduction only -3.5% (R6);
// all sort/phase locality schemes regressed (R2/R3/R4).

#define GDIM  96
#define NFEAT 16

typedef float f32x4 __attribute__((ext_vector_type(4)));

__device__ __forceinline__ int clampi(int v, int lo, int hi) {
    return v < lo ? lo : (v > hi ? hi : v);
}

__global__ __launch_bounds__(256) void grid_interp_v4(
    const f32x4* __restrict__ vox4,   // [8*96*96*96*4] float4
    const int*   __restrict__ gidx,
    const float* __restrict__ pts,
    f32x4*       __restrict__ out4,   // [N*4] float4
    int n_tasks)                       // N * 4
{
    const int tid = blockIdx.x * blockDim.x + threadIdx.x;
    if (tid >= n_tasks) return;

    const int p  = tid >> 2;   // point index
    const int fq = tid & 3;    // feature quad 0..3

    // 4 lanes of a point read the same addresses -> broadcast
    const float px = __builtin_nontemporal_load(&pts[p * 3 + 0]);
    const float py = __builtin_nontemporal_load(&pts[p * 3 + 1]);
    const float pz = __builtin_nontemporal_load(&pts[p * 3 + 2]);
    const int   gi = __builtin_nontemporal_load(&gidx[p]);

    // remap [-1,1] -> [0,1]
    const float ux = (px + 1.0f) * 0.5f;
    const float uy = (py + 1.0f) * 0.5f;
    const float uz = (pz + 1.0f) * 0.5f;
    const bool inside = (ux >= 0.0f) & (ux <= 1.0f) &
                        (uy >= 0.0f) & (uy <= 1.0f) &
                        (uz >= 0.0f) & (uz <= 1.0f);

    const float sx = ux * (float)(GDIM - 1);
    const float sy = uy * (float)(GDIM - 1);
    const float sz = uz * (float)(GDIM - 1);
    const int bx = (int)sx, by = (int)sy, bz = (int)sz;
    const float fx = sx - (float)bx;
    const float fy = sy - (float)by;
    const float fz = sz - (float)bz;

    const int gbase = gi * (GDIM * GDIM * GDIM);

    float ax = 0.f, ay = 0.f, az = 0.f, aw = 0.f;
#pragma unroll
    for (int k = 0; k < 8; ++k) {
        const int ox = k & 1, oy = (k >> 1) & 1, oz = (k >> 2) & 1;
        const int cx = clampi(bx + ox, 0, GDIM - 1);
        const int cy = clampi(by + oy, 0, GDIM - 1);
        const int cz = clampi(bz + oz, 0, GDIM - 1);
        const int cell = gbase + cx * (GDIM * GDIM) + cy * GDIM + cz;
        const f32x4 v = vox4[(size_t)(cell << 2) + fq];
        const float w = (ox ? fx : 1.0f - fx) *
                        (oy ? fy : 1.0f - fy) *
                        (oz ? fz : 1.0f - fz);
        ax = fmaf(v.x, w, ax);
        ay = fmaf(v.y, w, ay);
        az = fmaf(v.z, w, az);
        aw = fmaf(v.w, w, aw);
    }

    f32x4 r;
    r.x = inside ? ax : 0.f;
    r.y = inside ? ay : 0.f;
    r.z = inside ? az : 0.f;
    r.w = inside ? aw : 0.f;
    __builtin_nontemporal_store(r, &out4[tid]);
}

extern "C" void kernel_launch(void* const* d_in, const int* in_sizes, int n_in,
                              void* d_out, int out_size, void* d_ws, size_t ws_size,
                              hipStream_t stream) {
    const f32x4* vox4 = (const f32x4*)d_in[0];
    const int*   gidx = (const int*)  d_in[1];
    const float* pts  = (const float*)d_in[2];
    f32x4*       out4 = (f32x4*)d_out;

    const int n_pts   = in_sizes[1];   // N
    const int n_tasks = n_pts * 4;     // N * 4 feature-quads

    const int threads = 256;
    const int blocks  = (n_tasks + threads - 1) / threads;   // 16384 at N=1M

    grid_interp_v4<<<blocks, threads, 0, stream>>>(vox4, gidx, pts, out4, n_tasks);
}